// Round 6
// baseline (3949.053 us; speedup 1.0000x reference)
//
#include <hip/hip_runtime.h>
#include <hip/hip_bf16.h>

#define B_SZ 1024
#define L_SEQ 77
#define TXT_D 768
#define DM 512
#define NQ 64
#define NH 8
#define HEADD 64
#define DEPTH 3
#define MLP_D 1024
#define ATT_SCALE 0.125f
#define BL_ROWS (B_SZ * L_SEQ)   // 78848

typedef __attribute__((ext_vector_type(8))) short bf16x8;
typedef __attribute__((ext_vector_type(4))) float f32x4;
typedef __attribute__((ext_vector_type(8))) unsigned short ushort8v;
typedef __attribute__((ext_vector_type(4))) unsigned short ushort4v;

__device__ __forceinline__ float bf2f(unsigned short u) {
    return __uint_as_float(((unsigned)u) << 16);
}
__device__ __forceinline__ unsigned short f2bf(float f) {
    unsigned u = __float_as_uint(f);
    unsigned r = (u + 0x7FFFu + ((u >> 16) & 1u)) >> 16;
    return (unsigned short)r;
}
__device__ __forceinline__ float gelu_tanh(float t) {
    return 0.5f * t * (1.0f + tanhf(0.7978845608028654f * (t + 0.044715f * t * t * t)));
}
// async global->LDS, 16B per lane; lds base must be wave-uniform
__device__ __forceinline__ void gld16(const unsigned short* g, unsigned short* l) {
    __builtin_amdgcn_global_load_lds(
        (const __attribute__((address_space(1))) unsigned int*)g,
        (__attribute__((address_space(3))) unsigned int*)l, 16, 0, 0);
}

// ===================== 256x256 deep-pipelined bf16 MFMA GEMM =====================
// C[M,N] = A[M,K] @ BT[N,K]^T. 8 waves (2Mx4N), BK=32, 4 LDS K-tile buffers,
// counted vmcnt (never 0 in loop), raw s_barrier, setprio around MFMA.
// EPI 0: +bias ; 1: +bias+res fp32 ; 2: gelu(+bias) ; 3: +bias+pos[(m%64)*N+n]
// EPI 4: qkv split — n<1024 -> Cb[m][1024] (Q,K); n>=1024 -> VT[b][512][64]
template <int EPI, bool OBF>
__global__ __launch_bounds__(512, 2) void gemm256(
    const unsigned short* __restrict__ A,   // [M,K] bf16
    const unsigned short* __restrict__ BT,  // [N,K] bf16
    const float* __restrict__ bias,         // [N] or null
    const float* __restrict__ res,          // fp32 (EPI1/3) or VT base (EPI4)
    float* __restrict__ Cf, unsigned short* __restrict__ Cb,
    int M, int N, int K)
{
    __shared__ __align__(16) unsigned short ldsA[4][8192];  // 4 bufs x [256 rows][32 cols]
    __shared__ __align__(16) unsigned short ldsB[4][8192];  // 64B row stride: bank-balanced b128 reads

    int tid = threadIdx.x;
    int lane = tid & 63, wid = tid >> 6;
    int wr = wid >> 2, wc = wid & 3;        // wave tile: rows wr*128, cols wc*64
    int lr = lane & 15, hi = lane >> 4;

    // bijective XCD-aware block remap (m204)
    int nwg = gridDim.x, id = blockIdx.x;
    int xq = nwg >> 3, xr = nwg & 7;
    int xcd = id & 7, lid = id >> 3;
    int wg = (xcd < xr ? xcd * (xq + 1) : xr * (xq + 1) + (xcd - xr) * xq) + lid;
    int nbn = N >> 8;
    int m0 = (wg / nbn) << 8, n0 = (wg % nbn) << 8;

    // staging addresses: lane writes LDS bytes [tid*16 + issue*8192, +16)
    int r0 = tid >> 2;                      // row 0..127 (issue0); +128 issue1
    int gc = (tid & 3) * 8;                 // k-elem offset 0,8,16,24
    const unsigned short* gA = A  + (long)(m0 + r0) * K + gc;
    const unsigned short* gB = BT + (long)(n0 + r0) * K + gc;
    const long rowK128 = 128L * (long)K;
    int dstb = wid * 512;                   // wave-uniform LDS elem base (issue0)

    // fragment read bases (elems): row*32 + hi*8 — bank-balanced, no swizzle needed
    int abase = (wr * 128 + lr) * 32 + hi * 8;
    int bbase = (wc * 64 + lr) * 32 + hi * 8;

    f32x4 acc[8][4];
#pragma unroll
    for (int m = 0; m < 8; ++m)
#pragma unroll
        for (int n = 0; n < 4; ++n) acc[m][n] = (f32x4){0.f, 0.f, 0.f, 0.f};

    const int T = K >> 5;   // K-tiles of 32

#define STAGE(kt) { \
    int q_ = (kt) & 3; \
    const unsigned short* ga_ = gA + (long)(kt) * 32; \
    const unsigned short* gb_ = gB + (long)(kt) * 32; \
    gld16(ga_,           &ldsA[q_][dstb]); \
    gld16(ga_ + rowK128, &ldsA[q_][dstb + 4096]); \
    gld16(gb_,           &ldsB[q_][dstb]); \
    gld16(gb_ + rowK128, &ldsB[q_][dstb + 4096]); }

#define COMPUTE(t) { \
    int q_ = (t) & 3; \
    bf16x8 bfr_[4]; \
    _Pragma("unroll") \
    for (int n = 0; n < 4; ++n) bfr_[n] = *(const bf16x8*)&ldsB[q_][bbase + n * 512]; \
    __builtin_amdgcn_s_setprio(1); \
    _Pragma("unroll") \
    for (int m = 0; m < 8; ++m) { \
        bf16x8 af_ = *(const bf16x8*)&ldsA[q_][abase + m * 512]; \
        _Pragma("unroll") \
        for (int n = 0; n < 4; ++n) \
            acc[m][n] = __builtin_amdgcn_mfma_f32_16x16x32_bf16(af_, bfr_[n], acc[m][n], 0, 0, 0); \
    } \
    __builtin_amdgcn_s_setprio(0); }

#define GITER(t, NCNT, DOSTAGE) { \
    asm volatile("s_waitcnt vmcnt(" #NCNT ")" ::: "memory"); \
    __builtin_amdgcn_s_barrier(); \
    __builtin_amdgcn_sched_barrier(0); \
    if (DOSTAGE) STAGE((t) + 3); \
    COMPUTE(t); }

    // prologue: stage tiles 0,1,2 (12 glds per wave)
    STAGE(0); STAGE(1); STAGE(2);

    int t = 0;
    for (; t < T - 3; ++t) GITER(t, 8, true);
    GITER(T - 3, 8, false);
    GITER(T - 2, 4, false);
    GITER(T - 1, 0, false);

#undef GITER
#undef COMPUTE
#undef STAGE

    // epilogue
    int r4 = hi * 4;
#pragma unroll
    for (int n = 0; n < 4; ++n) {
        int col = n0 + wc * 64 + n * 16 + lr;
        float bv = bias ? bias[col] : 0.f;
#pragma unroll
        for (int m = 0; m < 8; ++m) {
#pragma unroll
            for (int r = 0; r < 4; ++r) {
                int row = m0 + wr * 128 + m * 16 + r4 + r;
                float val = acc[m][n][r] + bv;
                if (EPI == 1) val += res[(long)row * N + col];
                if (EPI == 3) val += res[(long)(row & (NQ - 1)) * N + col];
                if (EPI == 2) val = gelu_tanh(val);
                if (EPI == 4) {
                    if (col < 1024) Cb[(long)row * 1024 + col] = f2bf(val);
                    else ((unsigned short*)res)[((long)(row >> 6) * 512 + (col - 1024)) * 64 + (row & 63)] = f2bf(val);
                } else if (OBF) {
                    Cb[(long)row * N + col] = f2bf(val);
                } else {
                    Cf[(long)row * N + col] = val;
                }
            }
        }
    }
}

// ===================== MFMA self-attention =====================
// One wave per (b,h). qk [B*64][1024] bf16 (Q cols 0-511, K cols 512-1023);
// vt [B][512][64] bf16 (V^T per batch); out [B*64][512] bf16.
__global__ __launch_bounds__(256) void self_attn_mfma(
    const unsigned short* __restrict__ qk,
    const unsigned short* __restrict__ vt,
    unsigned short* __restrict__ o)
{
    __shared__ __align__(16) unsigned short p_lds[4][64][68];
    int tid = threadIdx.x, lane = tid & 63, wv = tid >> 6;
    int b = blockIdx.x >> 1;
    int h = (blockIdx.x & 1) * 4 + wv;
    int col0 = h * HEADD;
    int lr = lane & 15, g = lane >> 4, lk = g * 8;

    const unsigned short* qbase = qk + (long)b * 64 * 1024 + col0;
    const unsigned short* kbase = qbase + 512;

    f32x4 s[4][4];
#pragma unroll
    for (int i = 0; i < 4; ++i)
#pragma unroll
        for (int j = 0; j < 4; ++j) s[i][j] = (f32x4){0.f, 0.f, 0.f, 0.f};

#pragma unroll
    for (int ks = 0; ks < 2; ++ks) {
        bf16x8 aq[4], bk[4];
#pragma unroll
        for (int i = 0; i < 4; ++i)
            aq[i] = *(const bf16x8*)(qbase + (long)(i * 16 + lr) * 1024 + ks * 32 + lk);
#pragma unroll
        for (int j = 0; j < 4; ++j)
            bk[j] = *(const bf16x8*)(kbase + (long)(j * 16 + lr) * 1024 + ks * 32 + lk);
#pragma unroll
        for (int i = 0; i < 4; ++i)
#pragma unroll
            for (int j = 0; j < 4; ++j)
                s[i][j] = __builtin_amdgcn_mfma_f32_16x16x32_bf16(aq[i], bk[j], s[i][j], 0, 0, 0);
    }

#pragma unroll
    for (int i = 0; i < 4; ++i) {
#pragma unroll
        for (int r = 0; r < 4; ++r) {
            float m = fmaxf(fmaxf(s[i][0][r], s[i][1][r]), fmaxf(s[i][2][r], s[i][3][r]));
            m = fmaxf(m, __shfl_xor(m, 1, 64));
            m = fmaxf(m, __shfl_xor(m, 2, 64));
            m = fmaxf(m, __shfl_xor(m, 4, 64));
            m = fmaxf(m, __shfl_xor(m, 8, 64));
            float sum = 0.f;
#pragma unroll
            for (int j = 0; j < 4; ++j) {
                float e = __expf(ATT_SCALE * (s[i][j][r] - m));
                s[i][j][r] = e;
                sum += e;
            }
            sum += __shfl_xor(sum, 1, 64);
            sum += __shfl_xor(sum, 2, 64);
            sum += __shfl_xor(sum, 4, 64);
            sum += __shfl_xor(sum, 8, 64);
            float inv = 1.f / sum;
            int row = i * 16 + g * 4 + r;
#pragma unroll
            for (int j = 0; j < 4; ++j)
                p_lds[wv][row][j * 16 + lr] = f2bf(s[i][j][r] * inv);
        }
    }
    __syncthreads();

    f32x4 oa[4][4];
#pragma unroll
    for (int i = 0; i < 4; ++i)
#pragma unroll
        for (int j = 0; j < 4; ++j) oa[i][j] = (f32x4){0.f, 0.f, 0.f, 0.f};

#pragma unroll
    for (int ks = 0; ks < 2; ++ks) {
        bf16x8 ap[4], bv[4];
#pragma unroll
        for (int i = 0; i < 4; ++i)
            ap[i] = *(const bf16x8*)&p_lds[wv][i * 16 + lr][ks * 32 + lk];
#pragma unroll
        for (int j = 0; j < 4; ++j)
            bv[j] = *(const bf16x8*)(vt + ((long)b * 512 + col0 + j * 16 + lr) * 64 + ks * 32 + lk);
#pragma unroll
        for (int i = 0; i < 4; ++i)
#pragma unroll
            for (int j = 0; j < 4; ++j)
                oa[i][j] = __builtin_amdgcn_mfma_f32_16x16x32_bf16(ap[i], bv[j], oa[i][j], 0, 0, 0);
    }

    unsigned short* ob = o + (long)b * 64 * 512 + col0;
#pragma unroll
    for (int i = 0; i < 4; ++i)
#pragma unroll
        for (int j = 0; j < 4; ++j)
#pragma unroll
            for (int r = 0; r < 4; ++r)
                ob[(long)(i * 16 + g * 4 + r) * 512 + j * 16 + lr] = f2bf(oa[i][j][r]);
}

// ===================== QK^T GEMM: S[78848,64] = kbuf @ qbf^T, *0.125 =====================
__global__ __launch_bounds__(256) void qk_gemm(
    const unsigned short* __restrict__ A,
    const unsigned short* __restrict__ Bq,
    float* __restrict__ S)
{
    __shared__ __align__(16) unsigned short As[128 * 32];
    __shared__ __align__(16) unsigned short Bs[64 * 32];
    int tid = threadIdx.x, lane = tid & 63, wv = tid >> 6;
    int m0 = blockIdx.x * 128;
    int lr = lane & 15, lk = (lane >> 4) * 8;

    int segrow = lane >> 2, segcol = (lane & 3) * 8;
    const unsigned short* gA0 = A + (long)(m0 + wv * 16 + segrow) * 512 + segcol;
    const unsigned short* gA1 = gA0 + 64L * 512;
    const unsigned short* gB  = Bq + (long)(wv * 16 + segrow) * 512 + segcol;
    unsigned short* lA0 = &As[wv * 512];
    unsigned short* lA1 = &As[(wv + 4) * 512];
    unsigned short* lB  = &Bs[wv * 512];

    f32x4 acc[2][4];
#pragma unroll
    for (int i = 0; i < 2; ++i)
#pragma unroll
        for (int j = 0; j < 4; ++j) acc[i][j] = (f32x4){0.f, 0.f, 0.f, 0.f};

    for (int k0 = 0; k0 < 512; k0 += 32) {
        __syncthreads();
        gld16(gA0 + k0, lA0);
        gld16(gA1 + k0, lA1);
        gld16(gB + k0, lB);
        __syncthreads();
        bf16x8 af[2], bq[4];
#pragma unroll
        for (int i = 0; i < 2; ++i) af[i] = *(const bf16x8*)&As[(wv * 32 + i * 16 + lr) * 32 + lk];
#pragma unroll
        for (int j = 0; j < 4; ++j) bq[j] = *(const bf16x8*)&Bs[(j * 16 + lr) * 32 + lk];
#pragma unroll
        for (int i = 0; i < 2; ++i)
#pragma unroll
            for (int j = 0; j < 4; ++j)
                acc[i][j] = __builtin_amdgcn_mfma_f32_16x16x32_bf16(af[i], bq[j], acc[i][j], 0, 0, 0);
    }
    int crow = (lane >> 4) * 4;
#pragma unroll
    for (int i = 0; i < 2; ++i)
#pragma unroll
        for (int j = 0; j < 4; ++j)
#pragma unroll
            for (int r = 0; r < 4; ++r)
                S[(long)(m0 + wv * 32 + i * 16 + crow + r) * 64 + j * 16 + lr] = acc[i][j][r] * ATT_SCALE;
}

// ===================== masked softmax: S[b*77+l][q] -> P[b][q][96] bf16 =====================
__global__ __launch_bounds__(256) void softmax_kernel(
    const float* __restrict__ S, const int* __restrict__ caplen,
    unsigned short* __restrict__ P)
{
    __shared__ float Sl[77][65];
    __shared__ float red[256];
    __shared__ float gm[64], gi[64];
    int b = blockIdx.x, tid = threadIdx.x;
    int cap = caplen[b];
    for (int i = tid; i < 77 * 16; i += 256) {
        int r = i >> 4, c = (i & 15) << 2;
        *(float4*)&Sl[r][c] = *(const float4*)(S + ((long)b * 77 + r) * 64 + c);
    }
    __syncthreads();
    int q = tid & 63, ch = tid >> 6;
    int l0 = ch * 20;
    int l1 = l0 + 20; if (l1 > 77) l1 = 77;
    int lc = (l1 < cap) ? l1 : cap;
    float m = -1e30f;
    for (int l = l0; l < lc; ++l) m = fmaxf(m, Sl[l][q]);
    red[tid] = m;
    __syncthreads();
    if (tid < 64) gm[tid] = fmaxf(fmaxf(red[tid], red[tid + 64]), fmaxf(red[tid + 128], red[tid + 192]));
    __syncthreads();
    float mq = gm[q];
    float s = 0.f;
    for (int l = l0; l < lc; ++l) s += expf(Sl[l][q] - mq);
    red[tid] = s;
    __syncthreads();
    if (tid < 64) gi[tid] = 1.f / (red[tid] + red[tid + 64] + red[tid + 128] + red[tid + 192]);
    __syncthreads();
    float iq = gi[q];
    unsigned short* Pq = P + ((long)b * 64 + q) * 96;
    int w0 = ch * 24;
    for (int l = w0; l < w0 + 24; ++l) {
        float val = (l < cap) ? expf(Sl[l][q] - mq) * iq : 0.f;
        Pq[l] = f2bf(val);
    }
}

// ===================== PV: out[b*64+q][d] = P[b] @ VT cols, MFMA =====================
__global__ __launch_bounds__(256) void pv_kernel(
    const unsigned short* __restrict__ P,
    const unsigned short* __restrict__ VT,
    unsigned short* __restrict__ out)
{
    int b = blockIdx.x;
    int tid = threadIdx.x, lane = tid & 63, wv = tid >> 6;
    int lr = lane & 15, lk = (lane >> 4) * 8;
    int wc = wv * 128;

    f32x4 acc[4][8];
#pragma unroll
    for (int i = 0; i < 4; ++i)
#pragma unroll
        for (int j = 0; j < 8; ++j) acc[i][j] = (f32x4){0.f, 0.f, 0.f, 0.f};

    bf16x8 pa[4][3];
#pragma unroll
    for (int rt = 0; rt < 4; ++rt)
#pragma unroll
        for (int ks = 0; ks < 3; ++ks)
            pa[rt][ks] = *(const bf16x8*)(P + ((long)b * 64 + rt * 16 + lr) * 96 + ks * 32 + lk);

    const long col0 = (long)b * 77;
#pragma unroll
    for (int ks = 0; ks < 3; ++ks) {
#pragma unroll
        for (int ct = 0; ct < 8; ++ct) {
            bf16x8 vb = *(const bf16x8*)(VT + (long)(wc + ct * 16 + lr) * BL_ROWS + col0 + ks * 32 + lk);
#pragma unroll
            for (int rt = 0; rt < 4; ++rt)
                acc[rt][ct] = __builtin_amdgcn_mfma_f32_16x16x32_bf16(pa[rt][ks], vb, acc[rt][ct], 0, 0, 0);
        }
    }
    int crow = (lane >> 4) * 4;
#pragma unroll
    for (int rt = 0; rt < 4; ++rt)
#pragma unroll
        for (int ct = 0; ct < 8; ++ct)
#pragma unroll
            for (int r = 0; r < 4; ++r)
                out[(long)(b * 64 + rt * 16 + crow + r) * 512 + wc + ct * 16 + lr] = f2bf(acc[rt][ct][r]);
}

// ===================== fp32 GEMM (tiny q = mq@wq only) =====================
#define BM 64
#define BN 64
#define BK 16
template <int EPI>
__global__ __launch_bounds__(256) void gemm_kernel(
    const float* __restrict__ A, const float* __restrict__ Bm,
    const float* __restrict__ bias, const float* __restrict__ res,
    float* __restrict__ C, int M, int N, int K)
{
    __shared__ float As[BK][BM];
    __shared__ float Bs[BK][BN];
    int tid = threadIdx.x;
    int m0 = blockIdx.y * BM;
    int n0 = blockIdx.x * BN;
    int tx = tid & 15, ty = tid >> 4;

    float acc[4][4] = {};
    int arow = tid >> 2;
    int akk  = (tid & 3) << 2;
    int brow = tid >> 4;
    int bcol = (tid & 15) << 2;

    const float* Aptr = A + (long)(m0 + arow) * K + akk;
    const float* Bptr = Bm + (long)brow * N + n0 + bcol;

    for (int k0 = 0; k0 < K; k0 += BK) {
        float4 av = *(const float4*)(Aptr + k0);
        float4 bv = *(const float4*)(Bptr + (long)k0 * N);
        __syncthreads();
        As[akk + 0][arow] = av.x;
        As[akk + 1][arow] = av.y;
        As[akk + 2][arow] = av.z;
        As[akk + 3][arow] = av.w;
        *(float4*)&Bs[brow][bcol] = bv;
        __syncthreads();
#pragma unroll
        for (int k = 0; k < BK; ++k) {
            float4 a = *(const float4*)&As[k][ty << 2];
            float4 b = *(const float4*)&Bs[k][tx << 2];
            float ar[4] = {a.x, a.y, a.z, a.w};
            float br[4] = {b.x, b.y, b.z, b.w};
#pragma unroll
            for (int i = 0; i < 4; ++i)
#pragma unroll
                for (int j = 0; j < 4; ++j)
                    acc[i][j] += ar[i] * br[j];
        }
    }
#pragma unroll
    for (int i = 0; i < 4; ++i) {
        int m = m0 + (ty << 2) + i;
        float out[4];
#pragma unroll
        for (int j = 0; j < 4; ++j) {
            int n = n0 + (tx << 2) + j;
            float val = acc[i][j];
            if (bias) val += bias[n];
            out[j] = val;
        }
        float4 o4 = {out[0], out[1], out[2], out[3]};
        *(float4*)(C + (long)m * N + n0 + (tx << 2)) = o4;
    }
}

// ===================== weight transpose + cast =====================
__global__ __launch_bounds__(256) void transpose_w_kernel(
    const float* __restrict__ src, unsigned short* __restrict__ dst,
    int K, int N, long sstride, long dstride)
{
    __shared__ float t[32][33];
    int n0 = blockIdx.x * 32, k0 = blockIdx.y * 32;
    const float* s = src + blockIdx.z * sstride;
    unsigned short* d = dst + blockIdx.z * dstride;
    int tx = threadIdx.x & 31, ty = threadIdx.x >> 5;
#pragma unroll
    for (int r = 0; r < 32; r += 8)
        t[ty + r][tx] = s[(long)(k0 + ty + r) * N + n0 + tx];
    __syncthreads();
#pragma unroll
    for (int r = 0; r < 32; r += 8)
        d[(long)(n0 + ty + r) * K + k0 + tx] = f2bf(t[tx][ty + r]);
}

// ===================== fp32 -> bf16 cast =====================
__global__ __launch_bounds__(256) void cvt_kernel(
    const float* __restrict__ in, unsigned short* __restrict__ out, long n8)
{
    long i = (long)blockIdx.x * 256 + threadIdx.x;
    long stride = (long)gridDim.x * 256;
    for (; i < n8; i += stride) {
        float4 v0 = *(const float4*)(in + i * 8);
        float4 v1 = *(const float4*)(in + i * 8 + 4);
        ushort8v o;
        o[0] = f2bf(v0.x); o[1] = f2bf(v0.y); o[2] = f2bf(v0.z); o[3] = f2bf(v0.w);
        o[4] = f2bf(v1.x); o[5] = f2bf(v1.y); o[6] = f2bf(v1.z); o[7] = f2bf(v1.w);
        *(ushort8v*)(out + i * 8) = o;
    }
}

// ===================== LayerNorm =====================
template <bool OBF>
__global__ __launch_bounds__(256) void ln_kernel(
    const float* __restrict__ x, const float* __restrict__ s,
    const float* __restrict__ b, void* __restrict__ yv, int rows)
{
    int wave = threadIdx.x >> 6;
    int lane = threadIdx.x & 63;
    int row = blockIdx.x * 4 + wave;
    if (row >= rows) return;
    const float* xr = x + (long)row * DM;
    float4 v0 = *(const float4*)(xr + lane * 4);
    float4 v1 = *(const float4*)(xr + 256 + lane * 4);
    float sum = v0.x + v0.y + v0.z + v0.w + v1.x + v1.y + v1.z + v1.w;
    float sq = v0.x * v0.x + v0.y * v0.y + v0.z * v0.z + v0.w * v0.w +
               v1.x * v1.x + v1.y * v1.y + v1.z * v1.z + v1.w * v1.w;
#pragma unroll
    for (int off = 32; off; off >>= 1) {
        sum += __shfl_xor(sum, off, 64);
        sq  += __shfl_xor(sq,  off, 64);
    }
    float mean = sum * (1.0f / DM);
    float var = sq * (1.0f / DM) - mean * mean;
    float rs = rsqrtf(var + 1e-5f);
    int c0 = lane * 4, c1 = 256 + lane * 4;
    float o[8];
    o[0] = (v0.x - mean) * rs * s[c0 + 0] + b[c0 + 0];
    o[1] = (v0.y - mean) * rs * s[c0 + 1] + b[c0 + 1];
    o[2] = (v0.z - mean) * rs * s[c0 + 2] + b[c0 + 2];
    o[3] = (v0.w - mean) * rs * s[c0 + 3] + b[c0 + 3];
    o[4] = (v1.x - mean) * rs * s[c1 + 0] + b[c1 + 0];
    o[5] = (v1.y - mean) * rs * s[c1 + 1] + b[c1 + 1];
    o[6] = (v1.z - mean) * rs * s[c1 + 2] + b[c1 + 2];
    o[7] = (v1.w - mean) * rs * s[c1 + 3] + b[c1 + 3];
    if (OBF) {
        unsigned short* yr = (unsigned short*)yv + (long)row * DM;
        ushort4v p0 = {f2bf(o[0]), f2bf(o[1]), f2bf(o[2]), f2bf(o[3])};
        ushort4v p1 = {f2bf(o[4]), f2bf(o[5]), f2bf(o[6]), f2bf(o[7])};
        *(ushort4v*)(yr + c0) = p0;
        *(ushort4v*)(yr + c1) = p1;
    } else {
        float* yr = (float*)yv + (long)row * DM;
        float4 p0 = {o[0], o[1], o[2], o[3]};
        float4 p1 = {o[4], o[5], o[6], o[7]};
        *(float4*)(yr + c0) = p0;
        *(float4*)(yr + c1) = p1;
    }
}

// ===================== Launch =====================
extern "C" void kernel_launch(void* const* d_in, const int* in_sizes, int n_in,
                              void* d_out, int out_size, void* d_ws, size_t ws_size,
                              hipStream_t stream)
{
    const float* text_embed = (const float*)d_in[0];
    const int*   caption_len = (const int*)d_in[1];
    const float* in_w = (const float*)d_in[2];
    const float* in_b = (const float*)d_in[3];
    const float* mq = (const float*)d_in[4];
    const float* wq = (const float*)d_in[5];
    const float* wk = (const float*)d_in[6];
    const float* wv = (const float*)d_in[7];
    const float* cproj_w = (const float*)d_in[8];
    const float* cproj_b = (const float*)d_in[9];
    const float* pos = (const float*)d_in[10];
    const float* ln1_s = (const float*)d_in[11];
    const float* ln1_b = (const float*)d_in[12];
    const float* qkv_w = (const float*)d_in[13];
    const float* qkv_b = (const float*)d_in[14];
    const float* aproj_w = (const float*)d_in[15];
    const float* aproj_b = (const float*)d_in[16];
    const float* ln2_s = (const float*)d_in[17];
    const float* ln2_b = (const float*)d_in[18];
    const float* fc1_w = (const float*)d_in[19];
    const float* fc1_b = (const float*)d_in[20];
    const float* fc2_w = (const float*)d_in[21];
    const float* fc2_b = (const float*)d_in[22];
    const float* lnf_s = (const float*)d_in[23];
    const float* lnf_b = (const float*)d_in[24];

    const int BL = BL_ROWS;        // 78848
    const int BQ = B_SZ * NQ;      // 65536
    const long TE_N = (long)B_SZ * L_SEQ * TXT_D;

    // ---- workspace carve ----
    char* w = (char*)d_ws;
    unsigned short* regA = (unsigned short*)w;     w += 201326592;
    unsigned short* feat_bf = (unsigned short*)w;  w += (long)BL * DM * 2;
    unsigned short* kbuf = (unsigned short*)w;     w += (long)BL * DM * 2;
    unsigned short* VT = (unsigned short*)w;       w += (long)BL * DM * 2 + 256;
    unsigned short* ybuf = (unsigned short*)w;     w += (long)BQ * DM * 2;
    float* xbuf = (float*)w;                       w += (long)BQ * DM * 4;
    float* qbuf = (float*)w;                       w += (long)NQ * DM * 4;
    unsigned short* qbf = (unsigned short*)w;      w += (long)NQ * DM * 2;
    unsigned short* wT = (unsigned short*)w;
    unsigned short* in_wT  = wT;
    unsigned short* wkT    = in_wT + 512 * 768;
    unsigned short* wvT    = wkT + 512 * 512;
    unsigned short* cprojT = wvT + 512 * 512;
    unsigned short* qkvT   = cprojT + 512 * 512;
    unsigned short* aprojT = qkvT + 3 * 1536 * 512;
    unsigned short* fc1T   = aprojT + 3 * 512 * 512;
    unsigned short* fc2T   = fc1T + 3 * 1024 * 512;

    unsigned short* te_bf = regA;
    float* S_all = (float*)regA;
    unsigned short* Pbuf = (unsigned short*)((char*)regA + 25165824);
    unsigned short* qkbuf = regA;                                 // [B*NQ][1024]
    unsigned short* vtbuf = regA + 134217728 / 2;                 // [B][512][64]
    unsigned short* hbuf = regA;

    dim3 blk(256), blk2(512);

    // ---- weight transpose+cast ----
    transpose_w_kernel<<<dim3(512 / 32, TXT_D / 32, 1), blk, 0, stream>>>(in_w, in_wT, TXT_D, 512, 0, 0);
    transpose_w_kernel<<<dim3(512 / 32, 512 / 32, 1), blk, 0, stream>>>(wk, wkT, 512, 512, 0, 0);
    transpose_w_kernel<<<dim3(512 / 32, 512 / 32, 1), blk, 0, stream>>>(wv, wvT, 512, 512, 0, 0);
    transpose_w_kernel<<<dim3(512 / 32, 512 / 32, 1), blk, 0, stream>>>(cproj_w, cprojT, 512, 512, 0, 0);
    transpose_w_kernel<<<dim3(1536 / 32, 512 / 32, 3), blk, 0, stream>>>(qkv_w, qkvT, 512, 1536, 512L * 1536, 1536L * 512);
    transpose_w_kernel<<<dim3(512 / 32, 512 / 32, 3), blk, 0, stream>>>(aproj_w, aprojT, 512, 512, 512L * 512, 512L * 512);
    transpose_w_kernel<<<dim3(1024 / 32, 512 / 32, 3), blk, 0, stream>>>(fc1_w, fc1T, 512, 1024, 512L * 1024, 1024L * 512);
    transpose_w_kernel<<<dim3(512 / 32, 1024 / 32, 3), blk, 0, stream>>>(fc2_w, fc2T, 1024, 512, 1024L * 512, 512L * 1024);
    cvt_kernel<<<dim3(2048), blk, 0, stream>>>(text_embed, te_bf, TE_N / 8);
    gemm_kernel<0><<<dim3(DM / BN, 1), blk, 0, stream>>>(mq, wq, nullptr, nullptr, qbuf, NQ, DM, DM);
    cvt_kernel<<<dim3(16), blk, 0, stream>>>(qbuf, qbf, (long)NQ * DM / 8);

    // feat = te @ in_w + in_b
    gemm256<0, true><<<dim3((BL / 256) * (DM / 256)), blk2, 0, stream>>>(
        te_bf, in_wT, in_b, nullptr, nullptr, feat_bf, BL, DM, TXT_D);
    // k = feat @ wk
    gemm256<0, true><<<dim3((BL / 256) * (DM / 256)), blk2, 0, stream>>>(
        feat_bf, wkT, nullptr, nullptr, nullptr, kbuf, BL, DM, DM);
    // VT = (feat @ wv)^T == wvT @ feat^T
    gemm256<0, true><<<dim3((DM / 256) * (BL / 256)), blk2, 0, stream>>>(
        wvT, feat_bf, nullptr, nullptr, nullptr, VT, DM, BL, DM);
    // cross-attention: QK^T -> softmax -> PV
    qk_gemm<<<dim3(BL / 128), blk, 0, stream>>>(kbuf, qbf, S_all);
    softmax_kernel<<<dim3(B_SZ), blk, 0, stream>>>(S_all, caption_len, Pbuf);
    pv_kernel<<<dim3(B_SZ), blk, 0, stream>>>(Pbuf, VT, ybuf);
    // x = cross_out @ cproj + b + pos
    gemm256<3, false><<<dim3((BQ / 256) * (DM / 256)), blk2, 0, stream>>>(
        ybuf, cprojT, cproj_b, pos, xbuf, nullptr, BQ, DM, DM);

    for (int i = 0; i < DEPTH; ++i) {
        ln_kernel<true><<<dim3(BQ / 4), blk, 0, stream>>>(
            xbuf, ln1_s + i * DM, ln1_b + i * DM, ybuf, BQ);
        gemm256<4, true><<<dim3((BQ / 256) * (3 * DM / 256)), blk2, 0, stream>>>(
            ybuf, qkvT + (long)i * 1536 * 512, qkv_b + i * 3 * DM, (const float*)vtbuf,
            nullptr, qkbuf, BQ, 3 * DM, DM);
        self_attn_mfma<<<dim3(B_SZ * 2), blk, 0, stream>>>(qkbuf, vtbuf, ybuf);
        gemm256<1, false><<<dim3((BQ / 256) * (DM / 256)), blk2, 0, stream>>>(
            ybuf, aprojT + (long)i * 512 * 512, aproj_b + i * DM, xbuf,
            xbuf, nullptr, BQ, DM, DM);
        ln_kernel<true><<<dim3(BQ / 4), blk, 0, stream>>>(
            xbuf, ln2_s + i * DM, ln2_b + i * DM, ybuf, BQ);
        gemm256<2, true><<<dim3((BQ / 256) * (MLP_D / 256)), blk2, 0, stream>>>(
            ybuf, fc1T + (long)i * 1024 * 512, fc1_b + i * MLP_D, nullptr,
            nullptr, hbuf, BQ, MLP_D, DM);
        gemm256<1, false><<<dim3((BQ / 256) * (DM / 256)), blk2, 0, stream>>>(
            hbuf, fc2T + (long)i * 512 * 1024, fc2_b + i * DM, xbuf,
            xbuf, nullptr, BQ, DM, MLP_D);
    }
    ln_kernel<false><<<dim3(BQ / 4), blk, 0, stream>>>(
        xbuf, lnf_s, lnf_b, (float*)d_out, BQ);
}

// Round 7
// 3161.330 us; speedup vs baseline: 1.2492x; 1.2492x over previous
//
#include <hip/hip_runtime.h>
#include <hip/hip_bf16.h>

#define B_SZ 1024
#define L_SEQ 77
#define TXT_D 768
#define DM 512
#define NQ 64
#define NH 8
#define HEADD 64
#define DEPTH 3
#define MLP_D 1024
#define ATT_SCALE 0.125f
#define BL_ROWS (B_SZ * L_SEQ)   // 78848

typedef __attribute__((ext_vector_type(8))) short bf16x8;
typedef __attribute__((ext_vector_type(4))) float f32x4;
typedef __attribute__((ext_vector_type(8))) unsigned short ushort8v;
typedef __attribute__((ext_vector_type(4))) unsigned short ushort4v;

__device__ __forceinline__ float bf2f(unsigned short u) {
    return __uint_as_float(((unsigned)u) << 16);
}
__device__ __forceinline__ unsigned short f2bf(float f) {
    unsigned u = __float_as_uint(f);
    unsigned r = (u + 0x7FFFu + ((u >> 16) & 1u)) >> 16;
    return (unsigned short)r;
}
__device__ __forceinline__ float gelu_tanh(float t) {
    return 0.5f * t * (1.0f + tanhf(0.7978845608028654f * (t + 0.044715f * t * t * t)));
}
// async global->LDS, 16B per lane; lds base must be wave-uniform
__device__ __forceinline__ void gld16(const unsigned short* g, unsigned short* l) {
    __builtin_amdgcn_global_load_lds(
        (const __attribute__((address_space(1))) unsigned int*)g,
        (__attribute__((address_space(3))) unsigned int*)l, 16, 0, 0);
}

// ===================== bf16 MFMA GEMM (128², T3-min 2-phase dbuf) =====================
// C[M,N] = A[M,K] @ BT[N,K]^T. 128x128 tile, BK=32, 4 waves.
// Double-buffered LDS; stage(t+1) issued BEFORE compute(t); one __syncthreads per step.
// EPI 0: +bias ; 1: +bias+res fp32 ; 2: gelu(+bias) ; 3: +bias+pos[(m%64)*N+n]
// EPI 4: qkv split — n<1024 -> Cb[m][1024] (Q,K); n>=1024 -> VT[b][512][64]
template <int EPI, bool OBF>
__global__ __launch_bounds__(256) void gemm_mfma(
    const unsigned short* __restrict__ A,   // [M,K] bf16
    const unsigned short* __restrict__ BT,  // [N,K] bf16
    const float* __restrict__ bias,         // [N] or null
    const float* __restrict__ res,          // fp32 (EPI1/3) or VT base (EPI4)
    float* __restrict__ Cf, unsigned short* __restrict__ Cb,
    int M, int N, int K)
{
    __shared__ __align__(16) unsigned short As[2][4096];  // 2 bufs x [128 rows][32]
    __shared__ __align__(16) unsigned short Bs[2][4096];
    int tid = threadIdx.x;
    int m0 = blockIdx.y * 128, n0 = blockIdx.x * 128;
    int lane = tid & 63, wv = tid >> 6;
    int wr = (wv >> 1) * 64, wc = (wv & 1) * 64;
    int lr = lane & 15, lk = (lane >> 4) * 8;

    f32x4 acc[4][4];
#pragma unroll
    for (int i = 0; i < 4; ++i)
#pragma unroll
        for (int j = 0; j < 4; ++j) acc[i][j] = (f32x4){0.f, 0.f, 0.f, 0.f};

    int segrow = lane >> 2;            // 0..15
    int segcol = (lane & 3) * 8;       // 0,8,16,24
    const unsigned short* gA0 = A + (long)(m0 + wv * 16 + segrow) * K + segcol;
    const unsigned short* gA1 = gA0 + 64L * K;
    const unsigned short* gB0 = BT + (long)(n0 + wv * 16 + segrow) * K + segcol;
    const unsigned short* gB1 = gB0 + 64L * K;

#define STAGE(kt, q) { \
    gld16(gA0 + (long)(kt) * 32, &As[q][wv * 512]); \
    gld16(gA1 + (long)(kt) * 32, &As[q][(wv + 4) * 512]); \
    gld16(gB0 + (long)(kt) * 32, &Bs[q][wv * 512]); \
    gld16(gB1 + (long)(kt) * 32, &Bs[q][(wv + 4) * 512]); }

#define COMPUTE(q) { \
    bf16x8 af_[4], bf_[4]; \
    _Pragma("unroll") \
    for (int i = 0; i < 4; ++i) af_[i] = *(const bf16x8*)&As[q][(wr + i * 16 + lr) * 32 + lk]; \
    _Pragma("unroll") \
    for (int j = 0; j < 4; ++j) bf_[j] = *(const bf16x8*)&Bs[q][(wc + j * 16 + lr) * 32 + lk]; \
    _Pragma("unroll") \
    for (int i = 0; i < 4; ++i) \
        _Pragma("unroll") \
        for (int j = 0; j < 4; ++j) \
            acc[i][j] = __builtin_amdgcn_mfma_f32_16x16x32_bf16(af_[i], bf_[j], acc[i][j], 0, 0, 0); }

    const int T = K >> 5;
    STAGE(0, 0);
    __syncthreads();
    for (int t = 0; t < T - 1; ++t) {
        STAGE(t + 1, (t + 1) & 1);   // issue next-tile loads BEFORE compute
        COMPUTE(t & 1);
        __syncthreads();             // vmcnt(0)+lgkmcnt(0)+barrier: next buf ready
    }
    COMPUTE((T - 1) & 1);

#undef STAGE
#undef COMPUTE

    int crow = wr + (lane >> 4) * 4;
    int ccol = wc + lr;
#pragma unroll
    for (int j = 0; j < 4; ++j) {
        int n = n0 + ccol + j * 16;
        float bv = bias ? bias[n] : 0.f;
#pragma unroll
        for (int i = 0; i < 4; ++i) {
#pragma unroll
            for (int r = 0; r < 4; ++r) {
                int m = m0 + crow + i * 16 + r;
                float val = acc[i][j][r] + bv;
                if (EPI == 1) val += res[(long)m * N + n];
                if (EPI == 3) val += res[(long)(m & (NQ - 1)) * N + n];
                if (EPI == 2) val = gelu_tanh(val);
                if (EPI == 4) {
                    if (n < 1024) Cb[(long)m * 1024 + n] = f2bf(val);
                    else ((unsigned short*)res)[((long)(m >> 6) * 512 + (n - 1024)) * 64 + (m & 63)] = f2bf(val);
                } else if (OBF) {
                    Cb[(long)m * N + n] = f2bf(val);
                } else {
                    Cf[(long)m * N + n] = val;
                }
            }
        }
    }
}

// ===================== MFMA self-attention =====================
// One wave per (b,h). qk [B*64][1024] bf16 (Q cols 0-511, K cols 512-1023);
// vt [B][512][64] bf16 (V^T per batch); out [B*64][512] bf16.
__global__ __launch_bounds__(256) void self_attn_mfma(
    const unsigned short* __restrict__ qk,
    const unsigned short* __restrict__ vt,
    unsigned short* __restrict__ o)
{
    __shared__ __align__(16) unsigned short p_lds[4][64][68];
    int tid = threadIdx.x, lane = tid & 63, wv = tid >> 6;
    int b = blockIdx.x >> 1;
    int h = (blockIdx.x & 1) * 4 + wv;
    int col0 = h * HEADD;
    int lr = lane & 15, g = lane >> 4, lk = g * 8;

    const unsigned short* qbase = qk + (long)b * 64 * 1024 + col0;
    const unsigned short* kbase = qbase + 512;

    f32x4 s[4][4];
#pragma unroll
    for (int i = 0; i < 4; ++i)
#pragma unroll
        for (int j = 0; j < 4; ++j) s[i][j] = (f32x4){0.f, 0.f, 0.f, 0.f};

#pragma unroll
    for (int ks = 0; ks < 2; ++ks) {
        bf16x8 aq[4], bk[4];
#pragma unroll
        for (int i = 0; i < 4; ++i)
            aq[i] = *(const bf16x8*)(qbase + (long)(i * 16 + lr) * 1024 + ks * 32 + lk);
#pragma unroll
        for (int j = 0; j < 4; ++j)
            bk[j] = *(const bf16x8*)(kbase + (long)(j * 16 + lr) * 1024 + ks * 32 + lk);
#pragma unroll
        for (int i = 0; i < 4; ++i)
#pragma unroll
            for (int j = 0; j < 4; ++j)
                s[i][j] = __builtin_amdgcn_mfma_f32_16x16x32_bf16(aq[i], bk[j], s[i][j], 0, 0, 0);
    }

#pragma unroll
    for (int i = 0; i < 4; ++i) {
#pragma unroll
        for (int r = 0; r < 4; ++r) {
            float m = fmaxf(fmaxf(s[i][0][r], s[i][1][r]), fmaxf(s[i][2][r], s[i][3][r]));
            m = fmaxf(m, __shfl_xor(m, 1, 64));
            m = fmaxf(m, __shfl_xor(m, 2, 64));
            m = fmaxf(m, __shfl_xor(m, 4, 64));
            m = fmaxf(m, __shfl_xor(m, 8, 64));
            float sum = 0.f;
#pragma unroll
            for (int j = 0; j < 4; ++j) {
                float e = __expf(ATT_SCALE * (s[i][j][r] - m));
                s[i][j][r] = e;
                sum += e;
            }
            sum += __shfl_xor(sum, 1, 64);
            sum += __shfl_xor(sum, 2, 64);
            sum += __shfl_xor(sum, 4, 64);
            sum += __shfl_xor(sum, 8, 64);
            float inv = 1.f / sum;
            int row = i * 16 + g * 4 + r;
#pragma unroll
            for (int j = 0; j < 4; ++j)
                p_lds[wv][row][j * 16 + lr] = f2bf(s[i][j][r] * inv);
        }
    }
    __syncthreads();

    f32x4 oa[4][4];
#pragma unroll
    for (int i = 0; i < 4; ++i)
#pragma unroll
        for (int j = 0; j < 4; ++j) oa[i][j] = (f32x4){0.f, 0.f, 0.f, 0.f};

#pragma unroll
    for (int ks = 0; ks < 2; ++ks) {
        bf16x8 ap[4], bv[4];
#pragma unroll
        for (int i = 0; i < 4; ++i)
            ap[i] = *(const bf16x8*)&p_lds[wv][i * 16 + lr][ks * 32 + lk];
#pragma unroll
        for (int j = 0; j < 4; ++j)
            bv[j] = *(const bf16x8*)(vt + ((long)b * 512 + col0 + j * 16 + lr) * 64 + ks * 32 + lk);
#pragma unroll
        for (int i = 0; i < 4; ++i)
#pragma unroll
            for (int j = 0; j < 4; ++j)
                oa[i][j] = __builtin_amdgcn_mfma_f32_16x16x32_bf16(ap[i], bv[j], oa[i][j], 0, 0, 0);
    }

    unsigned short* ob = o + (long)b * 64 * 512 + col0;
#pragma unroll
    for (int i = 0; i < 4; ++i)
#pragma unroll
        for (int j = 0; j < 4; ++j)
#pragma unroll
            for (int r = 0; r < 4; ++r)
                ob[(long)(i * 16 + g * 4 + r) * 512 + j * 16 + lr] = f2bf(oa[i][j][r]);
}

// ===================== QK^T GEMM: S[78848,64] = kbuf @ qbf^T, *0.125 =====================
__global__ __launch_bounds__(256) void qk_gemm(
    const unsigned short* __restrict__ A,
    const unsigned short* __restrict__ Bq,
    float* __restrict__ S)
{
    __shared__ __align__(16) unsigned short As[128 * 32];
    __shared__ __align__(16) unsigned short Bs[64 * 32];
    int tid = threadIdx.x, lane = tid & 63, wv = tid >> 6;
    int m0 = blockIdx.x * 128;
    int lr = lane & 15, lk = (lane >> 4) * 8;

    int segrow = lane >> 2, segcol = (lane & 3) * 8;
    const unsigned short* gA0 = A + (long)(m0 + wv * 16 + segrow) * 512 + segcol;
    const unsigned short* gA1 = gA0 + 64L * 512;
    const unsigned short* gB  = Bq + (long)(wv * 16 + segrow) * 512 + segcol;
    unsigned short* lA0 = &As[wv * 512];
    unsigned short* lA1 = &As[(wv + 4) * 512];
    unsigned short* lB  = &Bs[wv * 512];

    f32x4 acc[2][4];
#pragma unroll
    for (int i = 0; i < 2; ++i)
#pragma unroll
        for (int j = 0; j < 4; ++j) acc[i][j] = (f32x4){0.f, 0.f, 0.f, 0.f};

    for (int k0 = 0; k0 < 512; k0 += 32) {
        __syncthreads();
        gld16(gA0 + k0, lA0);
        gld16(gA1 + k0, lA1);
        gld16(gB + k0, lB);
        __syncthreads();
        bf16x8 af[2], bq[4];
#pragma unroll
        for (int i = 0; i < 2; ++i) af[i] = *(const bf16x8*)&As[(wv * 32 + i * 16 + lr) * 32 + lk];
#pragma unroll
        for (int j = 0; j < 4; ++j) bq[j] = *(const bf16x8*)&Bs[(j * 16 + lr) * 32 + lk];
#pragma unroll
        for (int i = 0; i < 2; ++i)
#pragma unroll
            for (int j = 0; j < 4; ++j)
                acc[i][j] = __builtin_amdgcn_mfma_f32_16x16x32_bf16(af[i], bq[j], acc[i][j], 0, 0, 0);
    }
    int crow = (lane >> 4) * 4;
#pragma unroll
    for (int i = 0; i < 2; ++i)
#pragma unroll
        for (int j = 0; j < 4; ++j)
#pragma unroll
            for (int r = 0; r < 4; ++r)
                S[(long)(m0 + wv * 32 + i * 16 + crow + r) * 64 + j * 16 + lr] = acc[i][j][r] * ATT_SCALE;
}

// ===================== masked softmax: S[b*77+l][q] -> P[b][q][96] bf16 =====================
__global__ __launch_bounds__(256) void softmax_kernel(
    const float* __restrict__ S, const int* __restrict__ caplen,
    unsigned short* __restrict__ P)
{
    __shared__ float Sl[77][65];
    __shared__ float red[256];
    __shared__ float gm[64], gi[64];
    int b = blockIdx.x, tid = threadIdx.x;
    int cap = caplen[b];
    for (int i = tid; i < 77 * 16; i += 256) {
        int r = i >> 4, c = (i & 15) << 2;
        *(float4*)&Sl[r][c] = *(const float4*)(S + ((long)b * 77 + r) * 64 + c);
    }
    __syncthreads();
    int q = tid & 63, ch = tid >> 6;
    int l0 = ch * 20;
    int l1 = l0 + 20; if (l1 > 77) l1 = 77;
    int lc = (l1 < cap) ? l1 : cap;
    float m = -1e30f;
    for (int l = l0; l < lc; ++l) m = fmaxf(m, Sl[l][q]);
    red[tid] = m;
    __syncthreads();
    if (tid < 64) gm[tid] = fmaxf(fmaxf(red[tid], red[tid + 64]), fmaxf(red[tid + 128], red[tid + 192]));
    __syncthreads();
    float mq = gm[q];
    float s = 0.f;
    for (int l = l0; l < lc; ++l) s += expf(Sl[l][q] - mq);
    red[tid] = s;
    __syncthreads();
    if (tid < 64) gi[tid] = 1.f / (red[tid] + red[tid + 64] + red[tid + 128] + red[tid + 192]);
    __syncthreads();
    float iq = gi[q];
    unsigned short* Pq = P + ((long)b * 64 + q) * 96;
    int w0 = ch * 24;
    for (int l = w0; l < w0 + 24; ++l) {
        float val = (l < cap) ? expf(Sl[l][q] - mq) * iq : 0.f;
        Pq[l] = f2bf(val);
    }
}

// ===================== PV: out[b*64+q][d] = P[b] @ VT cols, MFMA =====================
__global__ __launch_bounds__(256) void pv_kernel(
    const unsigned short* __restrict__ P,
    const unsigned short* __restrict__ VT,
    unsigned short* __restrict__ out)
{
    int b = blockIdx.x;
    int tid = threadIdx.x, lane = tid & 63, wv = tid >> 6;
    int lr = lane & 15, lk = (lane >> 4) * 8;
    int wc = wv * 128;

    f32x4 acc[4][8];
#pragma unroll
    for (int i = 0; i < 4; ++i)
#pragma unroll
        for (int j = 0; j < 8; ++j) acc[i][j] = (f32x4){0.f, 0.f, 0.f, 0.f};

    bf16x8 pa[4][3];
#pragma unroll
    for (int rt = 0; rt < 4; ++rt)
#pragma unroll
        for (int ks = 0; ks < 3; ++ks)
            pa[rt][ks] = *(const bf16x8*)(P + ((long)b * 64 + rt * 16 + lr) * 96 + ks * 32 + lk);

    const long col0 = (long)b * 77;
#pragma unroll
    for (int ks = 0; ks < 3; ++ks) {
#pragma unroll
        for (int ct = 0; ct < 8; ++ct) {
            bf16x8 vb = *(const bf16x8*)(VT + (long)(wc + ct * 16 + lr) * BL_ROWS + col0 + ks * 32 + lk);
#pragma unroll
            for (int rt = 0; rt < 4; ++rt)
                acc[rt][ct] = __builtin_amdgcn_mfma_f32_16x16x32_bf16(pa[rt][ks], vb, acc[rt][ct], 0, 0, 0);
        }
    }
    int crow = (lane >> 4) * 4;
#pragma unroll
    for (int rt = 0; rt < 4; ++rt)
#pragma unroll
        for (int ct = 0; ct < 8; ++ct)
#pragma unroll
            for (int r = 0; r < 4; ++r)
                out[(long)(b * 64 + rt * 16 + crow + r) * 512 + wc + ct * 16 + lr] = f2bf(acc[rt][ct][r]);
}

// ===================== fp32 GEMM (tiny q = mq@wq only) =====================
#define BM 64
#define BN 64
#define BK 16
template <int EPI>
__global__ __launch_bounds__(256) void gemm_kernel(
    const float* __restrict__ A, const float* __restrict__ Bm,
    const float* __restrict__ bias, const float* __restrict__ res,
    float* __restrict__ C, int M, int N, int K)
{
    __shared__ float As[BK][BM];
    __shared__ float Bs[BK][BN];
    int tid = threadIdx.x;
    int m0 = blockIdx.y * BM;
    int n0 = blockIdx.x * BN;
    int tx = tid & 15, ty = tid >> 4;

    float acc[4][4] = {};
    int arow = tid >> 2;
    int akk  = (tid & 3) << 2;
    int brow = tid >> 4;
    int bcol = (tid & 15) << 2;

    const float* Aptr = A + (long)(m0 + arow) * K + akk;
    const float* Bptr = Bm + (long)brow * N + n0 + bcol;

    for (int k0 = 0; k0 < K; k0 += BK) {
        float4 av = *(const float4*)(Aptr + k0);
        float4 bv = *(const float4*)(Bptr + (long)k0 * N);
        __syncthreads();
        As[akk + 0][arow] = av.x;
        As[akk + 1][arow] = av.y;
        As[akk + 2][arow] = av.z;
        As[akk + 3][arow] = av.w;
        *(float4*)&Bs[brow][bcol] = bv;
        __syncthreads();
#pragma unroll
        for (int k = 0; k < BK; ++k) {
            float4 a = *(const float4*)&As[k][ty << 2];
            float4 b = *(const float4*)&Bs[k][tx << 2];
            float ar[4] = {a.x, a.y, a.z, a.w};
            float br[4] = {b.x, b.y, b.z, b.w};
#pragma unroll
            for (int i = 0; i < 4; ++i)
#pragma unroll
                for (int j = 0; j < 4; ++j)
                    acc[i][j] += ar[i] * br[j];
        }
    }
#pragma unroll
    for (int i = 0; i < 4; ++i) {
        int m = m0 + (ty << 2) + i;
        float out[4];
#pragma unroll
        for (int j = 0; j < 4; ++j) {
            int n = n0 + (tx << 2) + j;
            float val = acc[i][j];
            if (bias) val += bias[n];
            out[j] = val;
        }
        float4 o4 = {out[0], out[1], out[2], out[3]};
        *(float4*)(C + (long)m * N + n0 + (tx << 2)) = o4;
    }
}

// ===================== weight transpose + cast =====================
__global__ __launch_bounds__(256) void transpose_w_kernel(
    const float* __restrict__ src, unsigned short* __restrict__ dst,
    int K, int N, long sstride, long dstride)
{
    __shared__ float t[32][33];
    int n0 = blockIdx.x * 32, k0 = blockIdx.y * 32;
    const float* s = src + blockIdx.z * sstride;
    unsigned short* d = dst + blockIdx.z * dstride;
    int tx = threadIdx.x & 31, ty = threadIdx.x >> 5;
#pragma unroll
    for (int r = 0; r < 32; r += 8)
        t[ty + r][tx] = s[(long)(k0 + ty + r) * N + n0 + tx];
    __syncthreads();
#pragma unroll
    for (int r = 0; r < 32; r += 8)
        d[(long)(n0 + ty + r) * K + k0 + tx] = f2bf(t[tx][ty + r]);
}

// ===================== fp32 -> bf16 cast =====================
__global__ __launch_bounds__(256) void cvt_kernel(
    const float* __restrict__ in, unsigned short* __restrict__ out, long n8)
{
    long i = (long)blockIdx.x * 256 + threadIdx.x;
    long stride = (long)gridDim.x * 256;
    for (; i < n8; i += stride) {
        float4 v0 = *(const float4*)(in + i * 8);
        float4 v1 = *(const float4*)(in + i * 8 + 4);
        ushort8v o;
        o[0] = f2bf(v0.x); o[1] = f2bf(v0.y); o[2] = f2bf(v0.z); o[3] = f2bf(v0.w);
        o[4] = f2bf(v1.x); o[5] = f2bf(v1.y); o[6] = f2bf(v1.z); o[7] = f2bf(v1.w);
        *(ushort8v*)(out + i * 8) = o;
    }
}

// ===================== LayerNorm =====================
template <bool OBF>
__global__ __launch_bounds__(256) void ln_kernel(
    const float* __restrict__ x, const float* __restrict__ s,
    const float* __restrict__ b, void* __restrict__ yv, int rows)
{
    int wave = threadIdx.x >> 6;
    int lane = threadIdx.x & 63;
    int row = blockIdx.x * 4 + wave;
    if (row >= rows) return;
    const float* xr = x + (long)row * DM;
    float4 v0 = *(const float4*)(xr + lane * 4);
    float4 v1 = *(const float4*)(xr + 256 + lane * 4);
    float sum = v0.x + v0.y + v0.z + v0.w + v1.x + v1.y + v1.z + v1.w;
    float sq = v0.x * v0.x + v0.y * v0.y + v0.z * v0.z + v0.w * v0.w +
               v1.x * v1.x + v1.y * v1.y + v1.z * v1.z + v1.w * v1.w;
#pragma unroll
    for (int off = 32; off; off >>= 1) {
        sum += __shfl_xor(sum, off, 64);
        sq  += __shfl_xor(sq,  off, 64);
    }
    float mean = sum * (1.0f / DM);
    float var = sq * (1.0f / DM) - mean * mean;
    float rs = rsqrtf(var + 1e-5f);
    int c0 = lane * 4, c1 = 256 + lane * 4;
    float o[8];
    o[0] = (v0.x - mean) * rs * s[c0 + 0] + b[c0 + 0];
    o[1] = (v0.y - mean) * rs * s[c0 + 1] + b[c0 + 1];
    o[2] = (v0.z - mean) * rs * s[c0 + 2] + b[c0 + 2];
    o[3] = (v0.w - mean) * rs * s[c0 + 3] + b[c0 + 3];
    o[4] = (v1.x - mean) * rs * s[c1 + 0] + b[c1 + 0];
    o[5] = (v1.y - mean) * rs * s[c1 + 1] + b[c1 + 1];
    o[6] = (v1.z - mean) * rs * s[c1 + 2] + b[c1 + 2];
    o[7] = (v1.w - mean) * rs * s[c1 + 3] + b[c1 + 3];
    if (OBF) {
        unsigned short* yr = (unsigned short*)yv + (long)row * DM;
        ushort4v p0 = {f2bf(o[0]), f2bf(o[1]), f2bf(o[2]), f2bf(o[3])};
        ushort4v p1 = {f2bf(o[4]), f2bf(o[5]), f2bf(o[6]), f2bf(o[7])};
        *(ushort4v*)(yr + c0) = p0;
        *(ushort4v*)(yr + c1) = p1;
    } else {
        float* yr = (float*)yv + (long)row * DM;
        float4 p0 = {o[0], o[1], o[2], o[3]};
        float4 p1 = {o[4], o[5], o[6], o[7]};
        *(float4*)(yr + c0) = p0;
        *(float4*)(yr + c1) = p1;
    }
}

// ===================== Launch =====================
extern "C" void kernel_launch(void* const* d_in, const int* in_sizes, int n_in,
                              void* d_out, int out_size, void* d_ws, size_t ws_size,
                              hipStream_t stream)
{
    const float* text_embed = (const float*)d_in[0];
    const int*   caption_len = (const int*)d_in[1];
    const float* in_w = (const float*)d_in[2];
    const float* in_b = (const float*)d_in[3];
    const float* mq = (const float*)d_in[4];
    const float* wq = (const float*)d_in[5];
    const float* wk = (const float*)d_in[6];
    const float* wv = (const float*)d_in[7];
    const float* cproj_w = (const float*)d_in[8];
    const float* cproj_b = (const float*)d_in[9];
    const float* pos = (const float*)d_in[10];
    const float* ln1_s = (const float*)d_in[11];
    const float* ln1_b = (const float*)d_in[12];
    const float* qkv_w = (const float*)d_in[13];
    const float* qkv_b = (const float*)d_in[14];
    const float* aproj_w = (const float*)d_in[15];
    const float* aproj_b = (const float*)d_in[16];
    const float* ln2_s = (const float*)d_in[17];
    const float* ln2_b = (const float*)d_in[18];
    const float* fc1_w = (const float*)d_in[19];
    const float* fc1_b = (const float*)d_in[20];
    const float* fc2_w = (const float*)d_in[21];
    const float* fc2_b = (const float*)d_in[22];
    const float* lnf_s = (const float*)d_in[23];
    const float* lnf_b = (const float*)d_in[24];

    const int BL = BL_ROWS;        // 78848
    const int BQ = B_SZ * NQ;      // 65536
    const long TE_N = (long)B_SZ * L_SEQ * TXT_D;

    // ---- workspace carve ----
    char* w = (char*)d_ws;
    unsigned short* regA = (unsigned short*)w;     w += 201326592;
    unsigned short* feat_bf = (unsigned short*)w;  w += (long)BL * DM * 2;
    unsigned short* kbuf = (unsigned short*)w;     w += (long)BL * DM * 2;
    unsigned short* VT = (unsigned short*)w;       w += (long)BL * DM * 2 + 256;
    unsigned short* ybuf = (unsigned short*)w;     w += (long)BQ * DM * 2;
    float* xbuf = (float*)w;                       w += (long)BQ * DM * 4;
    float* qbuf = (float*)w;                       w += (long)NQ * DM * 4;
    unsigned short* qbf = (unsigned short*)w;      w += (long)NQ * DM * 2;
    unsigned short* wT = (unsigned short*)w;
    unsigned short* in_wT  = wT;
    unsigned short* wkT    = in_wT + 512 * 768;
    unsigned short* wvT    = wkT + 512 * 512;
    unsigned short* cprojT = wvT + 512 * 512;
    unsigned short* qkvT   = cprojT + 512 * 512;
    unsigned short* aprojT = qkvT + 3 * 1536 * 512;
    unsigned short* fc1T   = aprojT + 3 * 512 * 512;
    unsigned short* fc2T   = fc1T + 3 * 1024 * 512;

    unsigned short* te_bf = regA;
    float* S_all = (float*)regA;
    unsigned short* Pbuf = (unsigned short*)((char*)regA + 25165824);
    unsigned short* qkbuf = regA;                                 // [B*NQ][1024]
    unsigned short* vtbuf = regA + 134217728 / 2;                 // [B][512][64]
    unsigned short* hbuf = regA;

    dim3 blk(256);

    // ---- weight transpose+cast ----
    transpose_w_kernel<<<dim3(512 / 32, TXT_D / 32, 1), blk, 0, stream>>>(in_w, in_wT, TXT_D, 512, 0, 0);
    transpose_w_kernel<<<dim3(512 / 32, 512 / 32, 1), blk, 0, stream>>>(wk, wkT, 512, 512, 0, 0);
    transpose_w_kernel<<<dim3(512 / 32, 512 / 32, 1), blk, 0, stream>>>(wv, wvT, 512, 512, 0, 0);
    transpose_w_kernel<<<dim3(512 / 32, 512 / 32, 1), blk, 0, stream>>>(cproj_w, cprojT, 512, 512, 0, 0);
    transpose_w_kernel<<<dim3(1536 / 32, 512 / 32, 3), blk, 0, stream>>>(qkv_w, qkvT, 512, 1536, 512L * 1536, 1536L * 512);
    transpose_w_kernel<<<dim3(512 / 32, 512 / 32, 3), blk, 0, stream>>>(aproj_w, aprojT, 512, 512, 512L * 512, 512L * 512);
    transpose_w_kernel<<<dim3(1024 / 32, 512 / 32, 3), blk, 0, stream>>>(fc1_w, fc1T, 512, 1024, 512L * 1024, 1024L * 512);
    transpose_w_kernel<<<dim3(512 / 32, 1024 / 32, 3), blk, 0, stream>>>(fc2_w, fc2T, 1024, 512, 1024L * 512, 512L * 1024);
    cvt_kernel<<<dim3(2048), blk, 0, stream>>>(text_embed, te_bf, TE_N / 8);
    gemm_kernel<0><<<dim3(DM / BN, 1), blk, 0, stream>>>(mq, wq, nullptr, nullptr, qbuf, NQ, DM, DM);
    cvt_kernel<<<dim3(16), blk, 0, stream>>>(qbuf, qbf, (long)NQ * DM / 8);

    // feat = te @ in_w + in_b
    gemm_mfma<0, true><<<dim3(DM / 128, BL / 128), blk, 0, stream>>>(
        te_bf, in_wT, in_b, nullptr, nullptr, feat_bf, BL, DM, TXT_D);
    // k = feat @ wk
    gemm_mfma<0, true><<<dim3(DM / 128, BL / 128), blk, 0, stream>>>(
        feat_bf, wkT, nullptr, nullptr, nullptr, kbuf, BL, DM, DM);
    // VT = (feat @ wv)^T == wvT @ feat^T
    gemm_mfma<0, true><<<dim3(BL / 128, DM / 128), blk, 0, stream>>>(
        wvT, feat_bf, nullptr, nullptr, nullptr, VT, DM, BL, DM);
    // cross-attention: QK^T -> softmax -> PV
    qk_gemm<<<dim3(BL / 128), blk, 0, stream>>>(kbuf, qbf, S_all);
    softmax_kernel<<<dim3(B_SZ), blk, 0, stream>>>(S_all, caption_len, Pbuf);
    pv_kernel<<<dim3(B_SZ), blk, 0, stream>>>(Pbuf, VT, ybuf);
    // x = cross_out @ cproj + b + pos
    gemm_mfma<3, false><<<dim3(DM / 128, BQ / 128), blk, 0, stream>>>(
        ybuf, cprojT, cproj_b, pos, xbuf, nullptr, BQ, DM, DM);

    for (int i = 0; i < DEPTH; ++i) {
        ln_kernel<true><<<dim3(BQ / 4), blk, 0, stream>>>(
            xbuf, ln1_s + i * DM, ln1_b + i * DM, ybuf, BQ);
        gemm_mfma<4, true><<<dim3(3 * DM / 128, BQ / 128), blk, 0, stream>>>(
            ybuf, qkvT + (long)i * 1536 * 512, qkv_b + i * 3 * DM, (const float*)vtbuf,
            nullptr, qkbuf, BQ, 3 * DM, DM);
        self_attn_mfma<<<dim3(B_SZ * 2), blk, 0, stream>>>(qkbuf, vtbuf, ybuf);
        gemm_mfma<1, false><<<dim3(DM / 128, BQ / 128), blk, 0, stream>>>(
            ybuf, aprojT + (long)i * 512 * 512, aproj_b + i * DM, xbuf,
            xbuf, nullptr, BQ, DM, DM);
        ln_kernel<true><<<dim3(BQ / 4), blk, 0, stream>>>(
            xbuf, ln2_s + i * DM, ln2_b + i * DM, ybuf, BQ);
        gemm_mfma<2, true><<<dim3(MLP_D / 128, BQ / 128), blk, 0, stream>>>(
            ybuf, fc1T + (long)i * 1024 * 512, fc1_b + i * MLP_D, nullptr,
            nullptr, hbuf, BQ, MLP_D, DM);
        gemm_mfma<1, false><<<dim3(DM / 128, BQ / 128), blk, 0, stream>>>(
            hbuf, fc2T + (long)i * 512 * 1024, fc2_b + i * DM, xbuf,
            xbuf, nullptr, BQ, DM, MLP_D);
    }
    ln_kernel<false><<<dim3(BQ / 4), blk, 0, stream>>>(
        xbuf, lnf_s, lnf_b, (float*)d_out, BQ);
}